// Round 1
// baseline (459.135 us; speedup 1.0000x reference)
//
#include <hip/hip_runtime.h>

#define NLVL 14

// ---------------- block-aggregated stream compaction ----------------
// One atomicAdd per 1024-thread block instead of per wave/thread (G12).
template <int NW>
__device__ __forceinline__ int block_compact(bool pred, int* gcnt, int cap) {
    __shared__ int wbase[NW];
    __shared__ int blockBase;
    unsigned long long b = __ballot(pred);
    int wid = threadIdx.x >> 6;
    int lane = threadIdx.x & 63;
    int before = __popcll(b & ((1ull << lane) - 1ull));
    if (lane == 0) wbase[wid] = __popcll(b);
    __syncthreads();
    if (threadIdx.x == 0) {
        int tot = 0;
        for (int i = 0; i < NW; i++) { int t = wbase[i]; wbase[i] = tot; tot += t; }
        blockBase = (tot > 0) ? atomicAdd(gcnt, tot) : 0;
    }
    __syncthreads();
    if (!pred) return -1;
    int slot = blockBase + wbase[wid] + before;
    return (slot < cap) ? slot : -1;   // cap overflow -> treated as unmasked (never hit at these densities)
}

__global__ __launch_bounds__(1024) void k_compact0(
    const float* __restrict__ mask, int* __restrict__ idxmap,
    int* __restrict__ coords, int* __restrict__ cnt, int n, int cap) {
    int p = blockIdx.x * 1024 + threadIdx.x;
    bool pred = (p < n) && (mask[p] > 0.5f);
    int slot = block_compact<16>(pred, cnt, cap);
    if (p < n) idxmap[p] = slot;
    if (slot >= 0) coords[slot] = p;
}

// mask_i(r,c) = max over 2x2 children of mask_{i-1}  (reduce_window SAME)
__global__ __launch_bounds__(1024) void k_downcompact(
    const int* __restrict__ idx_prev, int Hp,
    int* __restrict__ idxmap, int* __restrict__ coords, int* __restrict__ cnt,
    int H, int cap) {
    int p = blockIdx.x * 1024 + threadIdx.x;
    bool pred = false;
    if (p < H * H) {
        int r = p / H, c = p - r * H;
        #pragma unroll
        for (int dr = 0; dr < 2; dr++) {
            #pragma unroll
            for (int dc = 0; dc < 2; dc++) {
                int rr = 2 * r + dr, cc = 2 * c + dc;
                if (rr < Hp && cc < Hp) pred |= (idx_prev[rr * Hp + cc] >= 0);
            }
        }
    }
    int slot = block_compact<16>(pred, cnt, cap);
    if (p < H * H) idxmap[p] = slot;
    if (slot >= 0) coords[slot] = p;
}

// level-0: 5x5 conv, 1 -> 32 channels, gather from dense x at masked slots.
// thread = slot*32 + ch
__global__ void k_conv0(const float* __restrict__ x, const float* __restrict__ w1,
                        const int* __restrict__ coords, const int* __restrict__ cnt, int cap,
                        float* __restrict__ vals, int H) {
    int t = blockIdx.x * 256 + threadIdx.x;
    int s = t >> 5, ch = t & 31;
    int n = *cnt; if (n > cap) n = cap;
    if (s >= n) return;
    int p = coords[s];
    int r = p / H, c = p - r * H;
    float acc = 0.f;
    #pragma unroll
    for (int a = 0; a < 5; a++) {
        int rr = r + a - 2;
        if ((unsigned)rr >= (unsigned)H) continue;
        #pragma unroll
        for (int b = 0; b < 5; b++) {
            int cc = c + b - 2;
            if ((unsigned)cc >= (unsigned)H) continue;
            acc = fmaf(x[rr * H + cc], w1[(a * 5 + b) * 32 + ch], acc);
        }
    }
    vals[(size_t)s * 32 + ch] = fmaxf(acc, 0.f);
}

// level-i (i>=1): stride-2 3x3 conv, 32 -> 32, gather via idxmap of previous level.
// out(r,c) = sum_{a,b} in(2r+a-1, 2c+b-1) * w[a][b][cin][cout]
__global__ void k_convi(const float* __restrict__ vprev, const int* __restrict__ idx_prev, int Hp,
                        const float* __restrict__ w,
                        const int* __restrict__ coords, const int* __restrict__ cnt, int cap,
                        float* __restrict__ vals, int H) {
    int t = blockIdx.x * 256 + threadIdx.x;
    int s = t >> 5, co = t & 31;
    int n = *cnt; if (n > cap) n = cap;
    if (s >= n) return;
    int p = coords[s];
    int r = p / H, c = p - r * H;
    float acc = 0.f;
    #pragma unroll
    for (int a = 0; a < 3; a++) {
        int rr = 2 * r + a - 1;
        if ((unsigned)rr >= (unsigned)Hp) continue;
        #pragma unroll
        for (int b = 0; b < 3; b++) {
            int cc = 2 * c + b - 1;
            if ((unsigned)cc >= (unsigned)Hp) continue;
            int j = idx_prev[rr * Hp + cc];
            if (j < 0) continue;
            const float* vp = vprev + (size_t)j * 32;
            const float* wp = w + (a * 3 + b) * 32 * 32 + co;
            #pragma unroll
            for (int ci = 0; ci < 32; ci++)
                acc = fmaf(vp[ci], wp[ci * 32], acc);
        }
    }
    vals[(size_t)s * 32 + co] = fmaxf(acc, 0.f);
}

// fused pooling: 14 levels x 32 slot-chunks of blocks; LDS reduce then one atomic/ch.
struct PoolArgs {
    unsigned long long voff[NLVL];
    int cap[NLVL];
};

__global__ void k_pool(const char* __restrict__ ws, PoolArgs pa,
                       const int* __restrict__ cnt, float* __restrict__ poolsum) {
    __shared__ float red[256];
    int lvl = blockIdx.x >> 5;
    int chunk = blockIdx.x & 31;
    const float* vals = (const float*)(ws + pa.voff[lvl]);
    int n = cnt[lvl]; if (n > pa.cap[lvl]) n = pa.cap[lvl];
    int ch = threadIdx.x & 31;
    int s0 = chunk * 8 + (threadIdx.x >> 5);
    float acc = 0.f;
    for (int s = s0; s < n; s += 256)
        acc += vals[(size_t)s * 32 + ch];
    red[threadIdx.x] = acc;
    __syncthreads();
    if (threadIdx.x < 32) {
        float tot = 0.f;
        #pragma unroll
        for (int g = 0; g < 8; g++) tot += red[threadIdx.x + 32 * g];
        if (tot != 0.f) atomicAdd(&poolsum[lvl * 32 + threadIdx.x], tot);
        else            atomicAdd(&poolsum[lvl * 32 + threadIdx.x], 0.f);
    }
}

// MLP: feat(448) -> relu(@wm1+bm1)(256) -> @wm2+bm2 (128). Single block.
__global__ void k_mlp(const float* __restrict__ poolsum, const int* __restrict__ cnt,
                      const float* __restrict__ wm1, const float* __restrict__ bm1,
                      const float* __restrict__ wm2, const float* __restrict__ bm2,
                      float* __restrict__ out) {
    __shared__ float feat[448];
    __shared__ float h[256];
    int tid = threadIdx.x;
    for (int k = tid; k < 448; k += 256) {
        int lvl = k >> 5;
        float c = (float)cnt[lvl];
        if (c < 1.f) c = 1.f;
        feat[k] = poolsum[k] / c;
    }
    __syncthreads();
    float acc = bm1[tid];
    for (int k = 0; k < 448; k++)
        acc = fmaf(feat[k], wm1[k * 256 + tid], acc);
    h[tid] = fmaxf(acc, 0.f);
    __syncthreads();
    if (tid < 128) {
        float o = bm2[tid];
        for (int j = 0; j < 256; j++)
            o = fmaf(h[j], wm2[j * 128 + tid], o);
        out[tid] = o;
    }
}

extern "C" void kernel_launch(void* const* d_in, const int* in_sizes, int n_in,
                              void* d_out, int out_size, void* d_ws, size_t ws_size,
                              hipStream_t stream) {
    const float* x    = (const float*)d_in[0];
    const float* mask = (const float*)d_in[1];
    const float* w1   = (const float*)d_in[2];
    const float* ws_w = (const float*)d_in[3];   // (13,3,3,32,32)
    const float* wm1  = (const float*)d_in[4];
    const float* bm1  = (const float*)d_in[5];
    const float* wm2  = (const float*)d_in[6];
    const float* bm2  = (const float*)d_in[7];
    float* out = (float*)d_out;
    char* ws = (char*)d_ws;

    int Hs[NLVL];
    Hs[0] = 2048;
    for (int i = 1; i < NLVL; i++) Hs[i] = (Hs[i - 1] + 1) / 2;

    // ws layout: [cnt:16 ints][poolsum:448 f32] then per level idxmap/coords/vals
    size_t cnt_off = 0, pool_off = 64;
    size_t off = 2048;
    size_t idx_off[NLVL], coord_off[NLVL], val_off[NLVL];
    int caps[NLVL];
    for (int i = 0; i < NLVL; i++) {
        size_t S = (size_t)Hs[i] * Hs[i];
        caps[i] = (S < 65536) ? (int)S : 65536;   // >100 sigma above expected masked counts
        idx_off[i] = off;   off += S * 4;               off = (off + 255) & ~(size_t)255;
        coord_off[i] = off; off += (size_t)caps[i] * 4; off = (off + 255) & ~(size_t)255;
        val_off[i] = off;   off += (size_t)caps[i] * 32 * 4; off = (off + 255) & ~(size_t)255;
    }
    // total ~60 MB

    int* cnt = (int*)(ws + cnt_off);
    float* poolsum = (float*)(ws + pool_off);
    hipMemsetAsync(ws, 0, 2048, stream);   // zero cnt + poolsum (ws is poisoned every call)

    {   // level 0
        int n = Hs[0] * Hs[0];
        k_compact0<<<(n + 1023) / 1024, 1024, 0, stream>>>(
            mask, (int*)(ws + idx_off[0]), (int*)(ws + coord_off[0]), cnt + 0, n, caps[0]);
        int gb = (caps[0] * 32 + 255) / 256;
        k_conv0<<<gb, 256, 0, stream>>>(
            x, w1, (const int*)(ws + coord_off[0]), cnt + 0, caps[0],
            (float*)(ws + val_off[0]), Hs[0]);
    }
    for (int i = 1; i < NLVL; i++) {
        int n = Hs[i] * Hs[i];
        k_downcompact<<<(n + 1023) / 1024, 1024, 0, stream>>>(
            (const int*)(ws + idx_off[i - 1]), Hs[i - 1],
            (int*)(ws + idx_off[i]), (int*)(ws + coord_off[i]), cnt + i, Hs[i], caps[i]);
        int gb = (caps[i] * 32 + 255) / 256;
        k_convi<<<gb, 256, 0, stream>>>(
            (const float*)(ws + val_off[i - 1]), (const int*)(ws + idx_off[i - 1]), Hs[i - 1],
            ws_w + (size_t)(i - 1) * 9 * 32 * 32,
            (const int*)(ws + coord_off[i]), cnt + i, caps[i],
            (float*)(ws + val_off[i]), Hs[i]);
    }

    PoolArgs pa;
    for (int i = 0; i < NLVL; i++) { pa.voff[i] = (unsigned long long)val_off[i]; pa.cap[i] = caps[i]; }
    k_pool<<<NLVL * 32, 256, 0, stream>>>((const char*)ws, pa, cnt, poolsum);
    k_mlp<<<1, 256, 0, stream>>>(poolsum, cnt, wm1, bm1, wm2, bm2, out);
}